// Round 1
// baseline (2217.577 us; speedup 1.0000x reference)
//
#include <hip/hip_runtime.h>
#include <math.h>

// Mamba block, fp32 baseline.
// Pipeline:
//   1. xz  = x @ W_in.T + b_in                    (GEMM 2048x1024 -> 4096)
//   2. xcs = silu(causal_dwconv4(xc) + conv_b)    (fused elementwise)
//   3. dbu = xcs @ W_x.T + b_x                    (GEMM 2048x2048 -> 2080)
//   4. scan: delta = softplus(d_raw@W_dt.T+b_dt); s = exp(delta*A)*s + delta*B*u;
//      y = (sum_n s + u)*Dp * silu(z)             (fused, state in registers)
//   5. out = y @ W_out.T + b_out                  (GEMM 2048x2048 -> 1024)

#define BM 128
#define BN 128
#define BKK 8

__global__ __launch_bounds__(256) void sgemm_bias(
    const float* __restrict__ A, const float* __restrict__ W,
    const float* __restrict__ bias, float* __restrict__ C,
    int M, int N, int K)
{
    __shared__ float As[BKK][BM + 4];
    __shared__ float Bs[BKK][BN + 4];
    const int tid = threadIdx.x;
    const int tx = tid & 15;        // N dir, 0..15
    const int ty = tid >> 4;        // M dir, 0..15
    const int m0 = blockIdx.y * BM;
    const int n0 = blockIdx.x * BN;
    const int lr = tid >> 1;        // 0..127
    const int lc = (tid & 1) * 4;   // 0 or 4

    float acc[8][8];
    #pragma unroll
    for (int i = 0; i < 8; ++i)
        #pragma unroll
        for (int j = 0; j < 8; ++j) acc[i][j] = 0.f;

    const float* Ap = A + (size_t)(m0 + lr) * K + lc;
    const float* Wp = W + (size_t)(n0 + lr) * K + lc;
    const bool wok = (n0 + lr) < N;

    for (int k0 = 0; k0 < K; k0 += BKK) {
        float4 av = *(const float4*)(Ap + k0);
        float4 bv = make_float4(0.f, 0.f, 0.f, 0.f);
        if (wok) bv = *(const float4*)(Wp + k0);
        As[lc + 0][lr] = av.x; As[lc + 1][lr] = av.y;
        As[lc + 2][lr] = av.z; As[lc + 3][lr] = av.w;
        Bs[lc + 0][lr] = bv.x; Bs[lc + 1][lr] = bv.y;
        Bs[lc + 2][lr] = bv.z; Bs[lc + 3][lr] = bv.w;
        __syncthreads();
        #pragma unroll
        for (int kk = 0; kk < BKK; ++kk) {
            float a[8], bb[8];
            #pragma unroll
            for (int i = 0; i < 8; ++i) a[i] = As[kk][ty * 8 + i];
            #pragma unroll
            for (int j = 0; j < 8; ++j) bb[j] = Bs[kk][tx * 8 + j];
            #pragma unroll
            for (int i = 0; i < 8; ++i)
                #pragma unroll
                for (int j = 0; j < 8; ++j)
                    acc[i][j] = fmaf(a[i], bb[j], acc[i][j]);
        }
        __syncthreads();
    }

    if (n0 + tx * 8 < N) {  // N is a multiple of 8 -> whole 8-col strip in/out
        float bvals[8];
        #pragma unroll
        for (int j = 0; j < 8; ++j) bvals[j] = bias[n0 + tx * 8 + j];
        #pragma unroll
        for (int i = 0; i < 8; ++i) {
            float* Cp = C + (size_t)(m0 + ty * 8 + i) * N + n0 + tx * 8;
            #pragma unroll
            for (int j = 0; j < 8; ++j) Cp[j] = acc[i][j] + bvals[j];
        }
    }
}

__global__ __launch_bounds__(256) void conv_silu_kernel(
    const float* __restrict__ xz, const float* __restrict__ conv_w,
    const float* __restrict__ conv_b, float* __restrict__ xcs)
{
    const int D = 2048, L = 1024;
    int idx = blockIdx.x * 256 + threadIdx.x;
    int d = idx & (D - 1);
    int l = (idx >> 11) & (L - 1);
    int b = idx >> 21;
    float w0 = conv_w[d * 4 + 0], w1 = conv_w[d * 4 + 1];
    float w2 = conv_w[d * 4 + 2], w3 = conv_w[d * 4 + 3];
    const float* col = xz + (size_t)b * L * 4096 + d;
    float acc = conv_b[d];
    if (l >= 3) acc = fmaf(col[(size_t)(l - 3) * 4096], w0, acc);
    if (l >= 2) acc = fmaf(col[(size_t)(l - 2) * 4096], w1, acc);
    if (l >= 1) acc = fmaf(col[(size_t)(l - 1) * 4096], w2, acc);
    acc = fmaf(col[(size_t)l * 4096], w3, acc);
    float sig = 1.f / (1.f + expf(-acc));
    xcs[(size_t)(b * L + l) * D + d] = acc * sig;
}

__device__ __forceinline__ float softplusf(float x) {
    return (x > 20.f) ? x : log1pf(expf(x));
}

__global__ __launch_bounds__(256) void scan_kernel(
    const float* __restrict__ dbu, const float* __restrict__ xz,
    const float* __restrict__ W_dt, const float* __restrict__ b_dt,
    const float* __restrict__ A_log, const float* __restrict__ Dp,
    float* __restrict__ y)
{
    const int D = 2048, L = 1024, NDBU = 2080, NS = 16;
    const int b = blockIdx.x >> 3;
    const int d = (blockIdx.x & 7) * 256 + threadIdx.x;

    float wdt[NS], Aneg[NS], s[NS];
    #pragma unroll
    for (int n = 0; n < NS; ++n) {
        wdt[n] = W_dt[d * NS + n];
        Aneg[n] = -expf(A_log[d * NS + n]);
        s[n] = 0.f;
    }
    const float bdt = b_dt[d];
    const float dp = Dp[d];

    __shared__ float sbuf[32][33];  // 32 timesteps x (d_raw[16] || Bmat[16])

    for (int l0 = 0; l0 < L; l0 += 32) {
        __syncthreads();
        {
            int r = threadIdx.x >> 3;        // 0..31
            int c4 = (threadIdx.x & 7) * 4;  // 0..28
            float4 v = *(const float4*)(dbu + ((size_t)b * L + l0 + r) * NDBU + c4);
            sbuf[r][c4 + 0] = v.x; sbuf[r][c4 + 1] = v.y;
            sbuf[r][c4 + 2] = v.z; sbuf[r][c4 + 3] = v.w;
        }
        __syncthreads();
        for (int li = 0; li < 32; ++li) {
            const int l = l0 + li;
            const float u = dbu[((size_t)b * L + l) * NDBU + 32 + d];
            float accd = bdt;
            #pragma unroll
            for (int n = 0; n < NS; ++n) accd = fmaf(sbuf[li][n], wdt[n], accd);
            const float delta = softplusf(accd);
            const float du = delta * u;
            float sum = 0.f;
            #pragma unroll
            for (int n = 0; n < NS; ++n) {
                float dA = expf(delta * Aneg[n]);
                s[n] = fmaf(dA, s[n], du * sbuf[li][16 + n]);
                sum += s[n];
            }
            const float ycore = (sum + u) * dp;
            const float z = xz[((size_t)b * L + l) * 4096 + 2048 + d];
            const float sz = z / (1.f + expf(-z));
            y[((size_t)b * L + l) * D + d] = ycore * sz;
        }
    }
}

extern "C" void kernel_launch(void* const* d_in, const int* in_sizes, int n_in,
                              void* d_out, int out_size, void* d_ws, size_t ws_size,
                              hipStream_t stream) {
    const float* x      = (const float*)d_in[0];
    const float* W_in   = (const float*)d_in[1];
    const float* b_in   = (const float*)d_in[2];
    const float* conv_w = (const float*)d_in[3];
    const float* conv_b = (const float*)d_in[4];
    const float* W_x    = (const float*)d_in[5];
    const float* b_x    = (const float*)d_in[6];
    const float* W_dt   = (const float*)d_in[7];
    const float* b_dt   = (const float*)d_in[8];
    const float* A_log  = (const float*)d_in[9];
    const float* Dp     = (const float*)d_in[10];
    const float* W_out  = (const float*)d_in[11];
    const float* b_out  = (const float*)d_in[12];
    float* out = (float*)d_out;

    // workspace layout (floats): xz[2048*4096] | xcs[2048*2048] | dbu[2048*2080] | y[2048*2048]
    float* xz  = (float*)d_ws;
    float* xcs = xz + (size_t)2048 * 4096;
    float* dbu = xcs + (size_t)2048 * 2048;
    float* yb  = dbu + (size_t)2048 * 2080;

    dim3 blk(256);

    // 1. xz = x @ W_in.T + b_in   (M=2048, N=4096, K=1024)
    sgemm_bias<<<dim3(4096 / BN, 2048 / BM), blk, 0, stream>>>(
        x, W_in, b_in, xz, 2048, 4096, 1024);

    // 2. xcs = silu(conv(xc) + conv_b)
    conv_silu_kernel<<<(2 * 1024 * 2048) / 256, blk, 0, stream>>>(
        xz, conv_w, conv_b, xcs);

    // 3. dbu = xcs @ W_x.T + b_x  (M=2048, N=2080, K=2048)
    sgemm_bias<<<dim3((2080 + BN - 1) / BN, 2048 / BM), blk, 0, stream>>>(
        xcs, W_x, b_x, dbu, 2048, 2080, 2048);

    // 4. fused delta/scan/gate -> y
    scan_kernel<<<16, blk, 0, stream>>>(dbu, xz, W_dt, b_dt, A_log, Dp, yb);

    // 5. out = y @ W_out.T + b_out (M=2048, N=1024, K=2048)
    sgemm_bias<<<dim3(1024 / BN, 2048 / BM), blk, 0, stream>>>(
        yb, W_out, b_out, out, 2048, 1024, 2048);
}

// Round 2
// 996.694 us; speedup vs baseline: 2.2249x; 2.2249x over previous
//
#include <hip/hip_runtime.h>
#include <math.h>

// Mamba block, fp32. Chunked parallel scan (32 chunks x 32 steps).
//   1. xz  = x @ W_in.T + b_in                    (GEMM 2048x1024 -> 4096)
//   2. xcs = silu(causal_dwconv4(xc) + conv_b)    (fused elementwise)
//   3. dbu = xcs @ W_x.T + b_x                    (GEMM 2048x2048 -> 2080)
//   4a. pass1: per-chunk local scan -> (S = local final state, P = prod dA)
//   4b. mid:   chunk-level sequential combine -> carry-in per chunk
//   4c. pass2: local scan with carry-in -> y = (sum+u)*Dp*silu(z)
//   5. out = y @ W_out.T + b_out                  (GEMM 2048x2048 -> 1024)

#define BM 128
#define BN 128
#define BKK 8

#define NSTATE 16
#define NCHUNK 32
#define LCHUNK 32   // L / NCHUNK

__global__ __launch_bounds__(256) void sgemm_bias(
    const float* __restrict__ A, const float* __restrict__ W,
    const float* __restrict__ bias, float* __restrict__ C,
    int M, int N, int K)
{
    __shared__ float As[BKK][BM + 4];
    __shared__ float Bs[BKK][BN + 4];
    const int tid = threadIdx.x;
    const int tx = tid & 15;        // N dir, 0..15
    const int ty = tid >> 4;        // M dir, 0..15
    const int m0 = blockIdx.y * BM;
    const int n0 = blockIdx.x * BN;
    const int lr = tid >> 1;        // 0..127
    const int lc = (tid & 1) * 4;   // 0 or 4

    float acc[8][8];
    #pragma unroll
    for (int i = 0; i < 8; ++i)
        #pragma unroll
        for (int j = 0; j < 8; ++j) acc[i][j] = 0.f;

    const float* Ap = A + (size_t)(m0 + lr) * K + lc;
    const float* Wp = W + (size_t)(n0 + lr) * K + lc;
    const bool wok = (n0 + lr) < N;

    for (int k0 = 0; k0 < K; k0 += BKK) {
        float4 av = *(const float4*)(Ap + k0);
        float4 bv = make_float4(0.f, 0.f, 0.f, 0.f);
        if (wok) bv = *(const float4*)(Wp + k0);
        As[lc + 0][lr] = av.x; As[lc + 1][lr] = av.y;
        As[lc + 2][lr] = av.z; As[lc + 3][lr] = av.w;
        Bs[lc + 0][lr] = bv.x; Bs[lc + 1][lr] = bv.y;
        Bs[lc + 2][lr] = bv.z; Bs[lc + 3][lr] = bv.w;
        __syncthreads();
        #pragma unroll
        for (int kk = 0; kk < BKK; ++kk) {
            float a[8], bb[8];
            #pragma unroll
            for (int i = 0; i < 8; ++i) a[i] = As[kk][ty * 8 + i];
            #pragma unroll
            for (int j = 0; j < 8; ++j) bb[j] = Bs[kk][tx * 8 + j];
            #pragma unroll
            for (int i = 0; i < 8; ++i)
                #pragma unroll
                for (int j = 0; j < 8; ++j)
                    acc[i][j] = fmaf(a[i], bb[j], acc[i][j]);
        }
        __syncthreads();
    }

    if (n0 + tx * 8 < N) {  // N is a multiple of 8 -> whole 8-col strip in/out
        float bvals[8];
        #pragma unroll
        for (int j = 0; j < 8; ++j) bvals[j] = bias[n0 + tx * 8 + j];
        #pragma unroll
        for (int i = 0; i < 8; ++i) {
            float* Cp = C + (size_t)(m0 + ty * 8 + i) * N + n0 + tx * 8;
            #pragma unroll
            for (int j = 0; j < 8; ++j) Cp[j] = acc[i][j] + bvals[j];
        }
    }
}

__global__ __launch_bounds__(256) void conv_silu_kernel(
    const float* __restrict__ xz, const float* __restrict__ conv_w,
    const float* __restrict__ conv_b, float* __restrict__ xcs)
{
    const int D = 2048, L = 1024;
    int idx = blockIdx.x * 256 + threadIdx.x;
    int d = idx & (D - 1);
    int l = (idx >> 11) & (L - 1);
    int b = idx >> 21;
    float w0 = conv_w[d * 4 + 0], w1 = conv_w[d * 4 + 1];
    float w2 = conv_w[d * 4 + 2], w3 = conv_w[d * 4 + 3];
    const float* col = xz + (size_t)b * L * 4096 + d;
    float acc = conv_b[d];
    if (l >= 3) acc = fmaf(col[(size_t)(l - 3) * 4096], w0, acc);
    if (l >= 2) acc = fmaf(col[(size_t)(l - 2) * 4096], w1, acc);
    if (l >= 1) acc = fmaf(col[(size_t)(l - 1) * 4096], w2, acc);
    acc = fmaf(col[(size_t)l * 4096], w3, acc);
    float sig = 1.f / (1.f + expf(-acc));
    xcs[(size_t)(b * L + l) * D + d] = acc * sig;
}

__device__ __forceinline__ float softplusf(float x) {
    return (x > 20.f) ? x : log1pf(expf(x));
}

// ---- chunked scan ----
// pass1: local scan from s=0 over one chunk; emit S (final state) and P (prod dA).
__global__ __launch_bounds__(256) void scan_pass1(
    const float* __restrict__ dbu, const float* __restrict__ W_dt,
    const float* __restrict__ b_dt, const float* __restrict__ A_log,
    float* __restrict__ Sout, float* __restrict__ Pout)
{
    const int D = 2048, L = 1024, NDBU = 2080;
    const int g = blockIdx.x & 7;               // d-group
    const int c = (blockIdx.x >> 3) & (NCHUNK - 1);
    const int b = blockIdx.x >> 8;
    const int d = g * 256 + threadIdx.x;

    float wdt[NSTATE], Aneg[NSTATE], s[NSTATE], P[NSTATE];
    #pragma unroll
    for (int n = 0; n < NSTATE; ++n) {
        wdt[n] = W_dt[d * NSTATE + n];
        Aneg[n] = -expf(A_log[d * NSTATE + n]);
        s[n] = 0.f; P[n] = 1.f;
    }
    const float bdt = b_dt[d];

    __shared__ float sbuf[LCHUNK][33];  // d_raw[16] || Bmat[16]
    {
        int r = threadIdx.x >> 3;
        int c4 = (threadIdx.x & 7) * 4;
        float4 v = *(const float4*)(dbu + ((size_t)b * L + c * LCHUNK + r) * NDBU + c4);
        sbuf[r][c4 + 0] = v.x; sbuf[r][c4 + 1] = v.y;
        sbuf[r][c4 + 2] = v.z; sbuf[r][c4 + 3] = v.w;
    }
    __syncthreads();

    for (int li = 0; li < LCHUNK; ++li) {
        const int l = c * LCHUNK + li;
        const float u = dbu[((size_t)b * L + l) * NDBU + 32 + d];
        float accd = bdt;
        #pragma unroll
        for (int n = 0; n < NSTATE; ++n) accd = fmaf(sbuf[li][n], wdt[n], accd);
        const float delta = softplusf(accd);
        const float du = delta * u;
        #pragma unroll
        for (int n = 0; n < NSTATE; ++n) {
            float dA = expf(delta * Aneg[n]);
            s[n] = fmaf(dA, s[n], du * sbuf[li][16 + n]);
            P[n] *= dA;
        }
    }
    const size_t o = (((size_t)b * NCHUNK + c) * D + d) * NSTATE;
    #pragma unroll
    for (int n = 0; n < NSTATE; ++n) { Sout[o + n] = s[n]; Pout[o + n] = P[n]; }
}

// mid: per (b,d,n), sequentially combine chunks; write carry-in over P buffer.
__global__ __launch_bounds__(256) void scan_mid(
    const float* __restrict__ S, float* __restrict__ P)
{
    const int D = 2048;
    int idx = blockIdx.x * 256 + threadIdx.x;   // (b*D + d)*16 + n
    int n = idx & 15;
    int d = (idx >> 4) & (D - 1);
    int b = idx >> 15;
    float carry = 0.f;
    for (int c = 0; c < NCHUNK; ++c) {
        size_t o = (((size_t)b * NCHUNK + c) * D + d) * NSTATE + n;
        float Sv = S[o], Pv = P[o];
        P[o] = carry;                 // carry-in for chunk c
        carry = fmaf(Pv, carry, Sv);
    }
}

// pass2: local scan seeded with carry-in; produce gated y.
__global__ __launch_bounds__(256) void scan_pass2(
    const float* __restrict__ dbu, const float* __restrict__ xz,
    const float* __restrict__ W_dt, const float* __restrict__ b_dt,
    const float* __restrict__ A_log, const float* __restrict__ Dp,
    const float* __restrict__ CarryIn, float* __restrict__ y)
{
    const int D = 2048, L = 1024, NDBU = 2080;
    const int g = blockIdx.x & 7;
    const int c = (blockIdx.x >> 3) & (NCHUNK - 1);
    const int b = blockIdx.x >> 8;
    const int d = g * 256 + threadIdx.x;

    float wdt[NSTATE], Aneg[NSTATE], s[NSTATE];
    const size_t o = (((size_t)b * NCHUNK + c) * D + d) * NSTATE;
    #pragma unroll
    for (int n = 0; n < NSTATE; ++n) {
        wdt[n] = W_dt[d * NSTATE + n];
        Aneg[n] = -expf(A_log[d * NSTATE + n]);
        s[n] = CarryIn[o + n];
    }
    const float bdt = b_dt[d];
    const float dp = Dp[d];

    __shared__ float sbuf[LCHUNK][33];
    {
        int r = threadIdx.x >> 3;
        int c4 = (threadIdx.x & 7) * 4;
        float4 v = *(const float4*)(dbu + ((size_t)b * L + c * LCHUNK + r) * NDBU + c4);
        sbuf[r][c4 + 0] = v.x; sbuf[r][c4 + 1] = v.y;
        sbuf[r][c4 + 2] = v.z; sbuf[r][c4 + 3] = v.w;
    }
    __syncthreads();

    for (int li = 0; li < LCHUNK; ++li) {
        const int l = c * LCHUNK + li;
        const float u = dbu[((size_t)b * L + l) * NDBU + 32 + d];
        float accd = bdt;
        #pragma unroll
        for (int n = 0; n < NSTATE; ++n) accd = fmaf(sbuf[li][n], wdt[n], accd);
        const float delta = softplusf(accd);
        const float du = delta * u;
        float sum = 0.f;
        #pragma unroll
        for (int n = 0; n < NSTATE; ++n) {
            float dA = expf(delta * Aneg[n]);
            s[n] = fmaf(dA, s[n], du * sbuf[li][16 + n]);
            sum += s[n];
        }
        const float ycore = (sum + u) * dp;
        const float z = xz[((size_t)b * L + l) * 4096 + 2048 + d];
        const float sz = z / (1.f + expf(-z));
        y[((size_t)b * L + l) * D + d] = ycore * sz;
    }
}

extern "C" void kernel_launch(void* const* d_in, const int* in_sizes, int n_in,
                              void* d_out, int out_size, void* d_ws, size_t ws_size,
                              hipStream_t stream) {
    const float* x      = (const float*)d_in[0];
    const float* W_in   = (const float*)d_in[1];
    const float* b_in   = (const float*)d_in[2];
    const float* conv_w = (const float*)d_in[3];
    const float* conv_b = (const float*)d_in[4];
    const float* W_x    = (const float*)d_in[5];
    const float* b_x    = (const float*)d_in[6];
    const float* W_dt   = (const float*)d_in[7];
    const float* b_dt   = (const float*)d_in[8];
    const float* A_log  = (const float*)d_in[9];
    const float* Dp     = (const float*)d_in[10];
    const float* W_out  = (const float*)d_in[11];
    const float* b_out  = (const float*)d_in[12];
    float* out = (float*)d_out;

    // ws (floats): xz[2048*4096] | xcs[2048*2048] | dbu[2048*2080] | y[2048*2048]
    // xcs is dead after GEMM2 -> reuse for S|P (2 x 2*32*2048*16 floats = exactly xcs size)
    float* xz  = (float*)d_ws;
    float* xcs = xz + (size_t)2048 * 4096;
    float* dbu = xcs + (size_t)2048 * 2048;
    float* yb  = dbu + (size_t)2048 * 2080;
    float* Sb  = xcs;
    float* Pb  = xcs + (size_t)2 * NCHUNK * 2048 * NSTATE;

    dim3 blk(256);

    // 1. xz = x @ W_in.T + b_in   (M=2048, N=4096, K=1024)
    sgemm_bias<<<dim3(4096 / BN, 2048 / BM), blk, 0, stream>>>(
        x, W_in, b_in, xz, 2048, 4096, 1024);

    // 2. xcs = silu(conv(xc) + conv_b)
    conv_silu_kernel<<<(2 * 1024 * 2048) / 256, blk, 0, stream>>>(
        xz, conv_w, conv_b, xcs);

    // 3. dbu = xcs @ W_x.T + b_x  (M=2048, N=2080, K=2048)
    sgemm_bias<<<dim3((2080 + BN - 1) / BN, 2048 / BM), blk, 0, stream>>>(
        xcs, W_x, b_x, dbu, 2048, 2080, 2048);

    // 4. chunked scan
    scan_pass1<<<2 * NCHUNK * 8, blk, 0, stream>>>(dbu, W_dt, b_dt, A_log, Sb, Pb);
    scan_mid<<<(2 * 2048 * NSTATE) / 256, blk, 0, stream>>>(Sb, Pb);
    scan_pass2<<<2 * NCHUNK * 8, blk, 0, stream>>>(dbu, xz, W_dt, b_dt, A_log, Dp, Pb, yb);

    // 5. out = y @ W_out.T + b_out (M=2048, N=1024, K=2048)
    sgemm_bias<<<dim3(1024 / BN, 2048 / BM), blk, 0, stream>>>(
        yb, W_out, b_out, out, 2048, 1024, 2048);
}

// Round 3
// 376.140 us; speedup vs baseline: 5.8956x; 2.6498x over previous
//
#include <hip/hip_runtime.h>
#include <math.h>

// Mamba block. GEMMs on MFMA f16 split-2 (x = hi+lo, C = Ah*Wh + Ah*Wl + Al*Wh),
// chunked parallel scan, fused conv/silu.

typedef _Float16 half8 __attribute__((ext_vector_type(8)));
typedef float floatx4 __attribute__((ext_vector_type(4)));

#define NSTATE 16
#define NCHUNK 32
#define LCHUNK 32

// ---------------- MFMA GEMM: C[M,N] = A[M,K] @ W[N,K]^T + bias ----------------
#define TBM 128
#define TBN 128
#define TBK 32

__device__ __forceinline__ void stage_load16(const float* p, bool ok, float f[16]) {
    #pragma unroll
    for (int i = 0; i < 4; ++i) {
        float4 v = ok ? *(const float4*)(p + i * 4) : make_float4(0.f, 0.f, 0.f, 0.f);
        f[i * 4 + 0] = v.x; f[i * 4 + 1] = v.y;
        f[i * 4 + 2] = v.z; f[i * 4 + 3] = v.w;
    }
}

__device__ __forceinline__ void stage_write16(_Float16* hi_base, _Float16* lo_base,
                                              int srow, int shalf, int sswz,
                                              const float f[16]) {
    #pragma unroll
    for (int c = 0; c < 2; ++c) {
        half8 h, l;
        #pragma unroll
        for (int e = 0; e < 8; ++e) {
            float x = f[c * 8 + e];
            _Float16 hv = (_Float16)x;
            h[e] = hv;
            l[e] = (_Float16)(x - (float)hv);
        }
        int sc = (shalf * 2 + c) ^ sswz;   // XOR bank swizzle (16B chunks)
        *(half8*)(hi_base + srow * TBK + sc * 8) = h;
        *(half8*)(lo_base + srow * TBK + sc * 8) = l;
    }
}

__global__ __launch_bounds__(256) void hgemm_split(
    const float* __restrict__ A, const float* __restrict__ W,
    const float* __restrict__ bias, float* __restrict__ C,
    int M, int N, int K)
{
    __shared__ _Float16 lds[4 * TBM * TBK];
    _Float16* Ah = lds;
    _Float16* Al = lds + TBM * TBK;
    _Float16* Wh = lds + 2 * TBM * TBK;
    _Float16* Wl = lds + 3 * TBM * TBK;

    const int tid = threadIdx.x;
    const int lane = tid & 63;
    const int wid = tid >> 6;
    const int wm = wid >> 1;            // wave row 0..1
    const int wn = wid & 1;             // wave col 0..1
    const int m0 = blockIdx.y * TBM;
    const int n0 = blockIdx.x * TBN;

    const int srow = tid >> 1;          // staging row 0..127
    const int shalf = tid & 1;          // which 16-float half of the 32-wide row
    const int sswz = (srow >> 2) & 3;

    const int kg = lane >> 4;           // k-group 0..3
    const int fr = lane & 15;           // fragment row/col

    floatx4 acc[4][4];
    #pragma unroll
    for (int mi = 0; mi < 4; ++mi)
        #pragma unroll
        for (int ni = 0; ni < 4; ++ni)
            acc[mi][ni] = (floatx4){0.f, 0.f, 0.f, 0.f};

    const float* Ap = A + (size_t)(m0 + srow) * K + shalf * 16;
    const int wr = n0 + srow;
    const float* Wp = W + (size_t)wr * K + shalf * 16;
    const bool wok = wr < N;

    float fa[16], fw[16];
    stage_load16(Ap, true, fa);
    stage_load16(Wp, wok, fw);

    const int nks = K / TBK;
    for (int ks = 0; ks < nks; ++ks) {
        __syncthreads();                 // previous compute done reading LDS
        stage_write16(Ah, Al, srow, shalf, sswz, fa);
        stage_write16(Wh, Wl, srow, shalf, sswz, fw);
        __syncthreads();
        if (ks + 1 < nks) {              // issue next tile's global loads early
            stage_load16(Ap + (ks + 1) * TBK, true, fa);
            stage_load16(Wp + (ks + 1) * TBK, wok, fw);
        }
        half8 afh[4], afl[4], wfh[4], wfl[4];
        #pragma unroll
        for (int mi = 0; mi < 4; ++mi) {
            int row = wm * 64 + mi * 16 + fr;
            int off = row * TBK + ((kg ^ ((row >> 2) & 3)) << 3);
            afh[mi] = *(const half8*)(Ah + off);
            afl[mi] = *(const half8*)(Al + off);
        }
        #pragma unroll
        for (int ni = 0; ni < 4; ++ni) {
            int row = wn * 64 + ni * 16 + fr;
            int off = row * TBK + ((kg ^ ((row >> 2) & 3)) << 3);
            wfh[ni] = *(const half8*)(Wh + off);
            wfl[ni] = *(const half8*)(Wl + off);
        }
        #pragma unroll
        for (int mi = 0; mi < 4; ++mi)
            #pragma unroll
            for (int ni = 0; ni < 4; ++ni) {
                acc[mi][ni] = __builtin_amdgcn_mfma_f32_16x16x32_f16(
                    afh[mi], wfh[ni], acc[mi][ni], 0, 0, 0);
                acc[mi][ni] = __builtin_amdgcn_mfma_f32_16x16x32_f16(
                    afh[mi], wfl[ni], acc[mi][ni], 0, 0, 0);
                acc[mi][ni] = __builtin_amdgcn_mfma_f32_16x16x32_f16(
                    afl[mi], wfh[ni], acc[mi][ni], 0, 0, 0);
            }
    }

    // epilogue: C[m][n], n = lane&15 (col), m = kg*4 + reg (row) within 16x16
    #pragma unroll
    for (int ni = 0; ni < 4; ++ni) {
        int nn = n0 + wn * 64 + ni * 16 + fr;
        if (nn >= N) continue;
        float bv = bias[nn];
        #pragma unroll
        for (int mi = 0; mi < 4; ++mi) {
            int mm = m0 + wm * 64 + mi * 16 + kg * 4;
            float* Cp = C + (size_t)mm * N + nn;
            #pragma unroll
            for (int r = 0; r < 4; ++r)
                Cp[(size_t)r * N] = acc[mi][ni][r] + bv;
        }
    }
}

// ---------------- conv + silu ----------------
__global__ __launch_bounds__(256) void conv_silu_kernel(
    const float* __restrict__ xz, const float* __restrict__ conv_w,
    const float* __restrict__ conv_b, float* __restrict__ xcs)
{
    const int D = 2048, L = 1024;
    int idx = blockIdx.x * 256 + threadIdx.x;
    int d = idx & (D - 1);
    int l = (idx >> 11) & (L - 1);
    int b = idx >> 21;
    float w0 = conv_w[d * 4 + 0], w1 = conv_w[d * 4 + 1];
    float w2 = conv_w[d * 4 + 2], w3 = conv_w[d * 4 + 3];
    const float* col = xz + (size_t)b * L * 4096 + d;
    float acc = conv_b[d];
    if (l >= 3) acc = fmaf(col[(size_t)(l - 3) * 4096], w0, acc);
    if (l >= 2) acc = fmaf(col[(size_t)(l - 2) * 4096], w1, acc);
    if (l >= 1) acc = fmaf(col[(size_t)(l - 1) * 4096], w2, acc);
    acc = fmaf(col[(size_t)l * 4096], w3, acc);
    float sig = 1.f / (1.f + expf(-acc));
    xcs[(size_t)(b * L + l) * D + d] = acc * sig;
}

__device__ __forceinline__ float softplusf(float x) {
    return (x > 20.f) ? x : log1pf(expf(x));
}

// ---------------- chunked scan ----------------
__global__ __launch_bounds__(256) void scan_pass1(
    const float* __restrict__ dbu, const float* __restrict__ W_dt,
    const float* __restrict__ b_dt, const float* __restrict__ A_log,
    float* __restrict__ Sout, float* __restrict__ Pout)
{
    const int D = 2048, L = 1024, NDBU = 2080;
    const int g = blockIdx.x & 7;
    const int c = (blockIdx.x >> 3) & (NCHUNK - 1);
    const int b = blockIdx.x >> 8;
    const int d = g * 256 + threadIdx.x;

    float wdt[NSTATE], Aneg[NSTATE], s[NSTATE], P[NSTATE];
    #pragma unroll
    for (int n = 0; n < NSTATE; ++n) {
        wdt[n] = W_dt[d * NSTATE + n];
        Aneg[n] = -expf(A_log[d * NSTATE + n]);
        s[n] = 0.f; P[n] = 1.f;
    }
    const float bdt = b_dt[d];

    __shared__ float sbuf[LCHUNK][33];
    {
        int r = threadIdx.x >> 3;
        int c4 = (threadIdx.x & 7) * 4;
        float4 v = *(const float4*)(dbu + ((size_t)b * L + c * LCHUNK + r) * NDBU + c4);
        sbuf[r][c4 + 0] = v.x; sbuf[r][c4 + 1] = v.y;
        sbuf[r][c4 + 2] = v.z; sbuf[r][c4 + 3] = v.w;
    }
    __syncthreads();

    for (int li = 0; li < LCHUNK; ++li) {
        const int l = c * LCHUNK + li;
        const float u = dbu[((size_t)b * L + l) * NDBU + 32 + d];
        float accd = bdt;
        #pragma unroll
        for (int n = 0; n < NSTATE; ++n) accd = fmaf(sbuf[li][n], wdt[n], accd);
        const float delta = softplusf(accd);
        const float du = delta * u;
        #pragma unroll
        for (int n = 0; n < NSTATE; ++n) {
            float dA = expf(delta * Aneg[n]);
            s[n] = fmaf(dA, s[n], du * sbuf[li][16 + n]);
            P[n] *= dA;
        }
    }
    const size_t o = (((size_t)b * NCHUNK + c) * D + d) * NSTATE;
    #pragma unroll
    for (int n = 0; n < NSTATE; ++n) { Sout[o + n] = s[n]; Pout[o + n] = P[n]; }
}

__global__ __launch_bounds__(256) void scan_mid(
    const float* __restrict__ S, float* __restrict__ P)
{
    const int D = 2048;
    int idx = blockIdx.x * 256 + threadIdx.x;
    int n = idx & 15;
    int d = (idx >> 4) & (D - 1);
    int b = idx >> 15;
    float carry = 0.f;
    for (int c = 0; c < NCHUNK; ++c) {
        size_t o = (((size_t)b * NCHUNK + c) * D + d) * NSTATE + n;
        float Sv = S[o], Pv = P[o];
        P[o] = carry;
        carry = fmaf(Pv, carry, Sv);
    }
}

__global__ __launch_bounds__(256) void scan_pass2(
    const float* __restrict__ dbu, const float* __restrict__ xz,
    const float* __restrict__ W_dt, const float* __restrict__ b_dt,
    const float* __restrict__ A_log, const float* __restrict__ Dp,
    const float* __restrict__ CarryIn, float* __restrict__ y)
{
    const int D = 2048, L = 1024, NDBU = 2080;
    const int g = blockIdx.x & 7;
    const int c = (blockIdx.x >> 3) & (NCHUNK - 1);
    const int b = blockIdx.x >> 8;
    const int d = g * 256 + threadIdx.x;

    float wdt[NSTATE], Aneg[NSTATE], s[NSTATE];
    const size_t o = (((size_t)b * NCHUNK + c) * D + d) * NSTATE;
    #pragma unroll
    for (int n = 0; n < NSTATE; ++n) {
        wdt[n] = W_dt[d * NSTATE + n];
        Aneg[n] = -expf(A_log[d * NSTATE + n]);
        s[n] = CarryIn[o + n];
    }
    const float bdt = b_dt[d];
    const float dp = Dp[d];

    __shared__ float sbuf[LCHUNK][33];
    {
        int r = threadIdx.x >> 3;
        int c4 = (threadIdx.x & 7) * 4;
        float4 v = *(const float4*)(dbu + ((size_t)b * L + c * LCHUNK + r) * NDBU + c4);
        sbuf[r][c4 + 0] = v.x; sbuf[r][c4 + 1] = v.y;
        sbuf[r][c4 + 2] = v.z; sbuf[r][c4 + 3] = v.w;
    }
    __syncthreads();

    for (int li = 0; li < LCHUNK; ++li) {
        const int l = c * LCHUNK + li;
        const float u = dbu[((size_t)b * L + l) * NDBU + 32 + d];
        float accd = bdt;
        #pragma unroll
        for (int n = 0; n < NSTATE; ++n) accd = fmaf(sbuf[li][n], wdt[n], accd);
        const float delta = softplusf(accd);
        const float du = delta * u;
        float sum = 0.f;
        #pragma unroll
        for (int n = 0; n < NSTATE; ++n) {
            float dA = expf(delta * Aneg[n]);
            s[n] = fmaf(dA, s[n], du * sbuf[li][16 + n]);
            sum += s[n];
        }
        const float ycore = (sum + u) * dp;
        const float z = xz[((size_t)b * L + l) * 4096 + 2048 + d];
        const float sz = z / (1.f + expf(-z));
        y[((size_t)b * L + l) * D + d] = ycore * sz;
    }
}

extern "C" void kernel_launch(void* const* d_in, const int* in_sizes, int n_in,
                              void* d_out, int out_size, void* d_ws, size_t ws_size,
                              hipStream_t stream) {
    const float* x      = (const float*)d_in[0];
    const float* W_in   = (const float*)d_in[1];
    const float* b_in   = (const float*)d_in[2];
    const float* conv_w = (const float*)d_in[3];
    const float* conv_b = (const float*)d_in[4];
    const float* W_x    = (const float*)d_in[5];
    const float* b_x    = (const float*)d_in[6];
    const float* W_dt   = (const float*)d_in[7];
    const float* b_dt   = (const float*)d_in[8];
    const float* A_log  = (const float*)d_in[9];
    const float* Dp     = (const float*)d_in[10];
    const float* W_out  = (const float*)d_in[11];
    const float* b_out  = (const float*)d_in[12];
    float* out = (float*)d_out;

    // ws (floats): xz[2048*4096] | xcs[2048*2048] | dbu[2048*2080] | y[2048*2048]
    float* xz  = (float*)d_ws;
    float* xcs = xz + (size_t)2048 * 4096;
    float* dbu = xcs + (size_t)2048 * 2048;
    float* yb  = dbu + (size_t)2048 * 2080;
    float* Sb  = xcs;                                   // xcs dead after GEMM2
    float* Pb  = xcs + (size_t)2 * NCHUNK * 2048 * NSTATE;

    dim3 blk(256);

    // 1. xz = x @ W_in.T + b_in   (M=2048, N=4096, K=1024)
    hgemm_split<<<dim3(4096 / TBN, 2048 / TBM), blk, 0, stream>>>(
        x, W_in, b_in, xz, 2048, 4096, 1024);

    // 2. xcs = silu(conv(xc) + conv_b)
    conv_silu_kernel<<<(2 * 1024 * 2048) / 256, blk, 0, stream>>>(
        xz, conv_w, conv_b, xcs);

    // 3. dbu = xcs @ W_x.T + b_x  (M=2048, N=2080, K=2048)
    hgemm_split<<<dim3((2080 + TBN - 1) / TBN, 2048 / TBM), blk, 0, stream>>>(
        xcs, W_x, b_x, dbu, 2048, 2080, 2048);

    // 4. chunked scan
    scan_pass1<<<2 * NCHUNK * 8, blk, 0, stream>>>(dbu, W_dt, b_dt, A_log, Sb, Pb);
    scan_mid<<<(2 * 2048 * NSTATE) / 256, blk, 0, stream>>>(Sb, Pb);
    scan_pass2<<<2 * NCHUNK * 8, blk, 0, stream>>>(dbu, xz, W_dt, b_dt, A_log, Dp, Pb, yb);

    // 5. out = y @ W_out.T + b_out (M=2048, N=1024, K=2048)
    hgemm_split<<<dim3(1024 / TBN, 2048 / TBM), blk, 0, stream>>>(
        yb, W_out, b_out, out, 2048, 1024, 2048);
}